// Round 6
// baseline (69.674 us; speedup 1.0000x reference)
//
#include <hip/hip_runtime.h>
#include <hip/hip_cooperative_groups.h>
#include <math.h>

namespace cg = cooperative_groups;

#define SR      44100.0
#define T_LEN   441000
#define B_ROWS  32
#define NCH     13782            // chunks per row (32 samples each; last = 8)
#define GCH     (B_ROWS * NCH)   // 441024 global chunks
#define FNB     1723             // ceil(GCH/256)
#define NSCAN   1024             // scan blocks: 32 segments x 32 rows
#define FSEGW   432              // chunks per segment (seg 31: 390)
#define FROUNDS 8

// fused ws layout (floats)
#define FWS_T   0                // 1024*6 segment totals
#define FWS_F   8192             // GCH*6 finals -> entries in place

// fallback (round-5) ws layout
#define R5SEGCH 1724
#define R5ROUNDS 10
#define R5WS_T  0
#define R5WS_E  2048
#define R5WS_F  1576960
#define WPR     216
#define R5NBLK  1728

typedef __attribute__((address_space(1))) const void gconst_t;
typedef __attribute__((address_space(3))) void lds_t;
#define GL2LDS(gp, lp) __builtin_amdgcn_global_load_lds((gconst_t*)(gp), (lds_t*)(lp), 16, 0, 0)

// ---------------- shared helpers ----------------

#define COMPUTE_COEFS_TO_LDS(scoef, qs, gains) do { \
    if (threadIdx.x < 3) { \
      int f = threadIdx.x; \
      double cfq = 100.0 * exp(log(30.0) * (double)f / 3.0); \
      double w0 = 2.0 * M_PI * cfq / SR; \
      double alpha = sin(w0) / (2.0 * (double)qs[f]); \
      double Ag = exp((double)gains[f] * (2.302585092994045684 / 40.0)); \
      double a0 = 1.0 + alpha / Ag; \
      scoef[f*5+0] = (float)((1.0 + alpha * Ag) / a0); \
      scoef[f*5+1] = (float)((-2.0 * cos(w0)) / a0); \
      scoef[f*5+2] = (float)((1.0 - alpha * Ag) / a0); \
      scoef[f*5+3] = (float)((-2.0 * cos(w0)) / a0); \
      scoef[f*5+4] = (float)((1.0 - alpha / Ag) / a0); \
    } \
  } while (0)

#define LOAD_COEFS(cf) \
  const float b00=cf[0],b10=cf[1],b20=cf[2],a10=cf[3],a20=cf[4]; \
  const float b01=cf[5],b11=cf[6],b21=cf[7],a11=cf[8],a21=cf[9]; \
  const float b02=cf[10],b12=cf[11],b22=cf[12],a12=cf[13],a22=cf[14];

__device__ __forceinline__ float rfl(float v) {
  return __int_as_float(__builtin_amdgcn_readfirstlane(__float_as_int(v)));
}
#define LOAD_COEFS_RFL(cf) \
  const float b00=rfl(cf[0]),b10=rfl(cf[1]),b20=rfl(cf[2]),a10=rfl(cf[3]),a20=rfl(cf[4]); \
  const float b01=rfl(cf[5]),b11=rfl(cf[6]),b21=rfl(cf[7]),a11=rfl(cf[8]),a21=rfl(cf[9]); \
  const float b02=rfl(cf[10]),b12=rfl(cf[11]),b22=rfl(cf[12]),a12=rfl(cf[13]),a22=rfl(cf[14]);

#define CASCADE_STEP(xx) do { \
    float y1 = fmaf(b00, (xx), s11); \
    s11 = fmaf(-a10, y1, fmaf(b10, (xx), s21)); \
    s21 = fmaf(-a20, y1, b20 * (xx)); \
    float y2 = fmaf(b01, y1, s12); \
    s12 = fmaf(-a11, y2, fmaf(b11, y1, s22)); \
    s22 = fmaf(-a21, y2, b21 * y1); \
    y3 = fmaf(b02, y2, s13); \
    s13 = fmaf(-a12, y3, fmaf(b12, y2, s23)); \
    s23 = fmaf(-a22, y3, b22 * y2); \
  } while (0)

#define MV6(dst, M, v, add) do { \
    _Pragma("unroll") \
    for (int _i = 0; _i < 6; _i++) { \
      float _s = (add)[_i]; \
      _Pragma("unroll") \
      for (int _k = 0; _k < 6; _k++) _s = fmaf((M)[_i*6+_k], (v)[_k], _s); \
      (dst)[_i] = _s; \
    } \
  } while (0)

__device__ __forceinline__ void mm6d(const double* X, const double* Y, double* Z, int t) {
  if (t < 36) {
    int i = t / 6, j = t % 6;
    double s = 0.0;
    #pragma unroll
    for (int k = 0; k < 6; k++) s += X[i*6+k] * Y[k*6+j];
    Z[t] = s;
  }
}

// ================= FUSED COOPERATIVE KERNEL =================
// LDS map (floats): [0..4095] wave slabs (ph1/3) / scan bufs+doubles (ph2)
//   scoef@4096(16) sW@4112(36) sV@4148(288) sT@4436(192) sO@4628(6) sG@4640(36)

#define STAGE_IN(h) do { \
    _Pragma("unroll") \
    for (int i = 0; i < 4; i++) { \
      int t_ = (i << 6) + lane; \
      int c_ = t_ >> 3; \
      int q_ = (t_ & 7) ^ (c_ & 7); \
      int gc_ = wc0 + ((h) << 5) + c_; \
      unsigned r_ = (unsigned)gc_ / NCH; \
      int ci_ = gc_ - (int)r_ * NCH; \
      long s4_ = (long)r_ * 110250 + ci_ * 8 + q_; \
      if (gc_ < GCH && s4_ < 3528000L) GL2LDS(xp4 + s4_, slab + (t_ << 2)); \
    } \
  } while (0)

#define READ_HALF(h) do { \
    if ((lane >> 5) == (h) && cvalid) { \
      const float* rowp_ = slab + ((lane & 31) << 5); \
      int xr_ = lane & 7; \
      _Pragma("unroll") \
      for (int j4 = 0; j4 < 8; j4++) a[j4] = *(const float4*)(rowp_ + ((j4 ^ xr_) << 2)); \
    } \
  } while (0)

#define OUT_HALF(h) do { \
    if ((lane >> 5) == (h) && cvalid) { \
      float* rowp_ = slab + ((lane & 31) << 5); \
      int xr_ = lane & 7; \
      _Pragma("unroll") \
      for (int j4 = 0; j4 < 8; j4++) *(float4*)(rowp_ + ((j4 ^ xr_) << 2)) = a[j4]; \
    } \
  } while (0)

#define OUT_STORE(h) do { \
    _Pragma("unroll") \
    for (int i = 0; i < 4; i++) { \
      int t_ = (i << 6) + lane; \
      int c_ = t_ >> 3, q_ = t_ & 7; \
      int gs_ = (t_ & ~7) | (q_ ^ (c_ & 7)); \
      int gc_ = wc0 + ((h) << 5) + c_; \
      unsigned r_ = (unsigned)gc_ / NCH; \
      int ci_ = gc_ - (int)r_ * NCH; \
      int n4c_ = (ci_ == NCH - 1) ? 2 : 8; \
      if (gc_ < GCH && q_ < n4c_) \
        ((float4*)y)[(long)r_ * 110250 + ci_ * 8 + q_] = *(const float4*)(slab + (gs_ << 2)); \
    } \
  } while (0)

__global__ __launch_bounds__(256, 7) void fused(const float* __restrict__ x,
                                                const float* __restrict__ qs,
                                                const float* __restrict__ gains,
                                                float* __restrict__ y,
                                                float* __restrict__ ws) {
  cg::grid_group grid = cg::this_grid();
  __shared__ __align__(16) float smem[4736];
  const int tid = threadIdx.x;
  const int wib = tid >> 6, lane = tid & 63;
  float* slab  = smem + (wib << 10);
  float* scoef = smem + 4096;
  float* sW    = smem + 4112;
  float* sV    = smem + 4148;
  float* sT    = smem + 4436;
  float* sO    = smem + 4628;
  float* sG    = smem + 4640;
  const int wc0 = blockIdx.x * 256 + (wib << 6);
  const int gchunk = blockIdx.x * 256 + tid;
  const bool cvalid = gchunk < GCH;
  const float4* xp4 = (const float4*)x;
  float4 a[8];

  // ---------- phase 1: finals from zero entry, audio -> regs ----------
  STAGE_IN(0);
  COMPUTE_COEFS_TO_LDS(scoef, qs, gains);
  __syncthreads();
  READ_HALF(0);
  __syncthreads();
  STAGE_IN(1);
  __syncthreads();
  READ_HALF(1);
  LOAD_COEFS_RFL(scoef);
  {
    unsigned r = (unsigned)gchunk / NCH;
    int ci = gchunk - (int)r * NCH;
    int n4 = (ci == NCH - 1) ? 2 : 8;
    if (cvalid) {
      float s11=0,s21=0,s12=0,s22=0,s13=0,s23=0, y3;
      if (n4 == 8) {
        #pragma unroll
        for (int j4 = 0; j4 < 8; j4++) {
          CASCADE_STEP(a[j4].x); CASCADE_STEP(a[j4].y);
          CASCADE_STEP(a[j4].z); CASCADE_STEP(a[j4].w);
        }
      } else {
        CASCADE_STEP(a[0].x); CASCADE_STEP(a[0].y); CASCADE_STEP(a[0].z); CASCADE_STEP(a[0].w);
        CASCADE_STEP(a[1].x); CASCADE_STEP(a[1].y); CASCADE_STEP(a[1].z); CASCADE_STEP(a[1].w);
      }
      (void)y3;
      float2* F2 = (float2*)(ws + FWS_F + (long)gchunk * 6);
      F2[0] = make_float2(s11, s21); F2[1] = make_float2(s12, s22); F2[2] = make_float2(s13, s23);
    }
  }
  grid.sync();   // S1

  const bool isScan = blockIdx.x < NSCAN;
  if (isScan) {
    // ---------- phase 2a: per-block matrix setup (double) + fold + scan ----------
    double* D = (double*)smem;          // Da=D, Db=D+36, Dc=D+72, Dd=D+108, dco=D+144
    double* Da = D, *Db = D+36, *Dc = D+72, *Dd = D+108, *dco = D+144;
    if (tid < 3) {
      int f = tid;
      double cfq = 100.0 * exp(log(30.0) * (double)f / 3.0);
      double w0 = 2.0 * M_PI * cfq / SR;
      double alpha = sin(w0) / (2.0 * (double)qs[f]);
      double Ag = exp((double)gains[f] * (2.302585092994045684 / 40.0));
      double a0 = 1.0 + alpha / Ag;
      dco[f*5+0] = (1.0 + alpha * Ag) / a0;
      dco[f*5+1] = (-2.0 * cos(w0)) / a0;
      dco[f*5+2] = (1.0 - alpha * Ag) / a0;
      dco[f*5+3] = (-2.0 * cos(w0)) / a0;
      dco[f*5+4] = (1.0 - alpha / Ag) / a0;
    }
    __syncthreads();
    if (tid == 0) {
      double u[7] = {0,0,0,0,0,0,1};
      for (int f = 0; f < 3; f++) {
        double b0=dco[f*5+0], b1=dco[f*5+1], b2=dco[f*5+2], a1=dco[f*5+3], a2=dco[f*5+4];
        double yv[7], s1p[7], s2p[7];
        for (int i = 0; i < 7; i++) {
          yv[i]  = b0 * u[i] + ((i == 2*f)   ? 1.0 : 0.0);
          s1p[i] = b1 * u[i] + ((i == 2*f+1) ? 1.0 : 0.0) - a1 * yv[i];
          s2p[i] = b2 * u[i] - a2 * yv[i];
        }
        for (int i = 0; i < 6; i++) { Da[(2*f)*6+i] = s1p[i]; Da[(2*f+1)*6+i] = s2p[i]; }
        for (int i = 0; i < 7; i++) u[i] = yv[i];
      }
    }
    __syncthreads();
    mm6d(Da, Da, Db, tid); __syncthreads();   // A^2
    mm6d(Db, Db, Da, tid); __syncthreads();   // A^4
    mm6d(Da, Da, Db, tid); __syncthreads();   // A^8
    mm6d(Db, Db, Da, tid); __syncthreads();   // A^16
    mm6d(Da, Da, Db, tid); __syncthreads();   // A^32 = W (Db)
    if (tid < 36) { sW[tid] = (float)Db[tid]; Dc[tid] = (tid % 7 == 0) ? 1.0 : 0.0; }
    __syncthreads();
    mm6d(Db, Db, Da, tid); __syncthreads();   // W^2 (Da) = sV0
    {
      double* cur = Da; double* oth = Db; double* Gc = Dc; double* Gd = Dd;
      #pragma unroll
      for (int k = 0; k < FROUNDS; k++) {
        if (tid < 36) sV[k*36 + tid] = (float)cur[tid];
        if ((FSEGW >> (k + 1)) & 1) {            // 432 bits: k=3,4,6,7
          __syncthreads();
          mm6d(Gc, cur, Gd, tid); __syncthreads();
          double* tm = Gc; Gc = Gd; Gd = tm;
        }
        if (k < FROUNDS - 1) {
          __syncthreads();
          mm6d(cur, cur, oth, tid); __syncthreads();
          double* tm = cur; cur = oth; oth = tm;
        }
      }
      if (tid < 36) sG[tid] = (float)Gc[tid];
    }
    __syncthreads();

    int srow = blockIdx.x >> 5, seg = blockIdx.x & 31;
    int segstart = seg * FSEGW;
    int nact = (seg == 31) ? 195 : 216;
    float* bufA = smem;
    float* bufB = smem + 1792;
    float e_rel[6], f0[6];
    {
      float v[6] = {0,0,0,0,0,0};
      if (tid < nact) {
        const float4* Fp = (const float4*)(ws + FWS_F + ((long)srow*NCH + segstart + 2*tid) * 6);
        float4 l0 = Fp[0], l1 = Fp[1], l2 = Fp[2];
        f0[0]=l0.x; f0[1]=l0.y; f0[2]=l0.z; f0[3]=l0.w; f0[4]=l1.x; f0[5]=l1.y;
        float f1[6] = {l1.z, l1.w, l2.x, l2.y, l2.z, l2.w};
        MV6(v, sW, f0, f1);
      }
      #pragma unroll
      for (int i = 0; i < 6; i++) bufA[tid*7 + i] = v[i];
      __syncthreads();
      float* src = bufA; float* dst = bufB;
      for (int k = 0; k < FROUNDS; k++) {
        int d = 1 << k;
        float nv[6];
        if (tid >= d) { MV6(nv, sV + k*36, src + (tid-d)*7, src + tid*7); }
        else { 
          #pragma unroll
          for (int i = 0; i < 6; i++) nv[i] = src[tid*7 + i];
        }
        #pragma unroll
        for (int i = 0; i < 6; i++) dst[tid*7 + i] = nv[i];
        __syncthreads();
        float* tm = src; src = dst; dst = tm;
      }
      if (tid > 0) {
        #pragma unroll
        for (int i = 0; i < 6; i++) e_rel[i] = src[(tid-1)*7 + i];
      } else {
        #pragma unroll
        for (int i = 0; i < 6; i++) e_rel[i] = 0.0f;
      }
      if (tid == nact - 1) {
        #pragma unroll
        for (int i = 0; i < 6; i++) ws[FWS_T + (long)blockIdx.x * 6 + i] = src[tid*7 + i];
      }
    }
    grid.sync();   // S2
    // ---------- phase 2b: inject offsets, write entries ----------
    if (tid < 192) sT[tid] = ws[FWS_T + srow*192 + tid];
    __syncthreads();
    if (tid == 0) {
      float o[6] = {0,0,0,0,0,0};
      for (int s2 = 0; s2 < seg; s2++) {
        float no[6];
        MV6(no, sG, o, sT + s2*6);
        #pragma unroll
        for (int i = 0; i < 6; i++) o[i] = no[i];
      }
      #pragma unroll
      for (int i = 0; i < 6; i++) sO[i] = o[i];
    }
    __syncthreads();
    if (tid < nact) {
      float e[6];
      #pragma unroll
      for (int i = 0; i < 6; i++) e[i] = sO[i];
      float z6[6] = {0,0,0,0,0,0};
      for (int k = 0; k < FROUNDS; k++) {
        if ((tid >> k) & 1) {
          float ne[6];
          MV6(ne, sV + k*36, e, z6);
          #pragma unroll
          for (int i = 0; i < 6; i++) e[i] = ne[i];
        }
      }
      #pragma unroll
      for (int i = 0; i < 6; i++) e[i] += e_rel[i];
      float e1[6];
      MV6(e1, sW, e, f0);
      float4* Fp = (float4*)(ws + FWS_F + ((long)srow*NCH + segstart + 2*tid) * 6);
      Fp[0] = make_float4(e[0], e[1], e[2], e[3]);
      Fp[1] = make_float4(e[4], e[5], e1[0], e1[1]);
      Fp[2] = make_float4(e1[2], e1[3], e1[4], e1[5]);
    }
    grid.sync();   // S3
    // scan blocks retired audio regs: re-stage (L3-resident)
    STAGE_IN(0);
    __syncthreads();
    READ_HALF(0);
    __syncthreads();
    STAGE_IN(1);
    __syncthreads();
    READ_HALF(1);
  } else {
    grid.sync();   // S2
    grid.sync();   // S3
  }

  // ---------- phase 3: emit from entry states ----------
  {
    float e0=0,e1v=0,e2=0,e3=0,e4=0,e5=0;
    if (cvalid) {
      const float2* E = (const float2*)(ws + FWS_F + (long)gchunk * 6);
      float2 p0 = E[0], p1 = E[1], p2 = E[2];
      e0=p0.x; e1v=p0.y; e2=p1.x; e3=p1.y; e4=p2.x; e5=p2.y;
    }
    unsigned r = (unsigned)gchunk / NCH;
    int ci = gchunk - (int)r * NCH;
    int n4 = (ci == NCH - 1) ? 2 : 8;
    if (cvalid) {
      float s11=e0, s21=e1v, s12=e2, s22=e3, s13=e4, s23=e5;
      float y3;
      if (n4 == 8) {
        #pragma unroll
        for (int j4 = 0; j4 < 8; j4++) {
          float4 v = a[j4], o;
          CASCADE_STEP(v.x); o.x = y3;
          CASCADE_STEP(v.y); o.y = y3;
          CASCADE_STEP(v.z); o.z = y3;
          CASCADE_STEP(v.w); o.w = y3;
          a[j4] = o;
        }
      } else {
        float4 v = a[0], o;
        CASCADE_STEP(v.x); o.x = y3;
        CASCADE_STEP(v.y); o.y = y3;
        CASCADE_STEP(v.z); o.z = y3;
        CASCADE_STEP(v.w); o.w = y3;
        a[0] = o;
        v = a[1];
        CASCADE_STEP(v.x); o.x = y3;
        CASCADE_STEP(v.y); o.y = y3;
        CASCADE_STEP(v.z); o.z = y3;
        CASCADE_STEP(v.w); o.w = y3;
        a[1] = o;
      }
    }
  }
  __syncthreads();
  OUT_HALF(0);
  __syncthreads();
  OUT_STORE(0);
  __syncthreads();
  OUT_HALF(1);
  __syncthreads();
  OUT_STORE(1);
}

// ================= FALLBACK: verified round-5 path =================

__global__ __launch_bounds__(256) void kA_states(const float* __restrict__ x,
                                                 const float* __restrict__ qs,
                                                 const float* __restrict__ gains,
                                                 float* __restrict__ ws) {
  __shared__ float lds[4 * 2048];
  __shared__ float scoef[16];
  int wib = threadIdx.x >> 6, lane = threadIdx.x & 63;
  int gw = blockIdx.x * 4 + wib;
  int row = gw / WPR, wci = gw % WPR;
  long rowbase = (long)row * T_LEN;
  int s0 = wci << 11;
  int span4 = (min(2048, T_LEN - s0)) >> 2;
  const float4* xp = (const float4*)(x + rowbase + s0);
  float* slab = lds + (wib << 11);
  #pragma unroll
  for (int i = 0; i < 8; i++) {
    int s = (i << 6) + lane;
    int g = (s & ~7) | ((s & 7) ^ ((s >> 3) & 7));
    if (g < span4) GL2LDS(xp + g, slab + (i << 8));
  }
  COMPUTE_COEFS_TO_LDS(scoef, qs, gains);
  __syncthreads();
  int ci = (wci << 6) + lane;
  if (ci < NCH) {
    LOAD_COEFS(scoef);
    int rem = min(32, T_LEN - (ci << 5));
    int n4 = rem >> 2;
    const float* rowp = slab + (lane << 5);
    int xr = lane & 7;
    float s11=0,s21=0,s12=0,s22=0,s13=0,s23=0, y3;
    for (int j4 = 0; j4 < n4; j4++) {
      float4 v = *(const float4*)(rowp + ((j4 ^ xr) << 2));
      CASCADE_STEP(v.x); CASCADE_STEP(v.y); CASCADE_STEP(v.z); CASCADE_STEP(v.w);
    }
    (void)y3;
    float2* F = (float2*)(ws + R5WS_F + ((long)row * NCH + ci) * 6);
    F[0] = make_float2(s11, s21); F[1] = make_float2(s12, s22); F[2] = make_float2(s13, s23);
  }
}

template<bool WANT_G>
__device__ __forceinline__ void scan_setup(const float* qs, const float* gains, int t,
                                           double* Da, double* Db, double* Dc, double* Dd,
                                           float* sW, float (*sV)[36], float* sG) {
  __shared__ double dco[3][5];
  if (t < 3) {
    int f = t;
    double cfq = 100.0 * exp(log(30.0) * (double)f / 3.0);
    double w0 = 2.0 * M_PI * cfq / SR;
    double alpha = sin(w0) / (2.0 * (double)qs[f]);
    double Ag = exp((double)gains[f] * (2.302585092994045684 / 40.0));
    double a0 = 1.0 + alpha / Ag;
    dco[f][0] = (1.0 + alpha * Ag) / a0;
    dco[f][1] = (-2.0 * cos(w0)) / a0;
    dco[f][2] = (1.0 - alpha * Ag) / a0;
    dco[f][3] = (-2.0 * cos(w0)) / a0;
    dco[f][4] = (1.0 - alpha / Ag) / a0;
  }
  __syncthreads();
  if (t == 0) {
    double u[7] = {0,0,0,0,0,0,1};
    for (int f = 0; f < 3; f++) {
      double b0=dco[f][0], b1=dco[f][1], b2=dco[f][2], a1=dco[f][3], a2=dco[f][4];
      double yv[7], s1p[7], s2p[7];
      for (int i = 0; i < 7; i++) {
        yv[i]  = b0 * u[i] + ((i == 2*f)   ? 1.0 : 0.0);
        s1p[i] = b1 * u[i] + ((i == 2*f+1) ? 1.0 : 0.0) - a1 * yv[i];
        s2p[i] = b2 * u[i] - a2 * yv[i];
      }
      for (int i = 0; i < 6; i++) { Da[(2*f)*6+i] = s1p[i]; Da[(2*f+1)*6+i] = s2p[i]; }
      for (int i = 0; i < 7; i++) u[i] = yv[i];
    }
  }
  if (WANT_G && t < 36) Dc[t] = (t % 7 == 0) ? 1.0 : 0.0;
  __syncthreads();
  mm6d(Da, Da, Db, t); __syncthreads();
  mm6d(Db, Db, Da, t); __syncthreads();
  mm6d(Da, Da, Db, t); __syncthreads();
  mm6d(Db, Db, Da, t); __syncthreads();
  mm6d(Da, Da, Db, t); __syncthreads();
  if (t < 36) sW[t] = (float)Db[t];
  mm6d(Db, Db, Da, t); __syncthreads();
  double* cur = Da; double* oth = Db;
  double* Gc = Dc; double* Gd = Dd;
  #pragma unroll
  for (int k = 0; k < R5ROUNDS; k++) {
    if (t < 36) sV[k][t] = (float)cur[t];
    if (WANT_G && ((R5SEGCH >> (k + 1)) & 1)) {
      __syncthreads();
      mm6d(Gc, cur, Gd, t); __syncthreads();
      double* tm = Gc; Gc = Gd; Gd = tm;
    }
    if (k < R5ROUNDS - 1) {
      __syncthreads();
      mm6d(cur, cur, oth, t); __syncthreads();
      double* tm = cur; cur = oth; oth = tm;
    }
  }
  if (WANT_G && t < 36) sG[t] = (float)Gc[t];
  __syncthreads();
}

__global__ __launch_bounds__(1024) void kB1_scan(const float* __restrict__ qs,
                                                 const float* __restrict__ gains,
                                                 float* __restrict__ ws) {
  int seg = blockIdx.x & 7, row = blockIdx.x >> 3, t = threadIdx.x;
  __shared__ double Da[36], Db[36], Dc[36], Dd[36];
  __shared__ float sW[36], sV[R5ROUNDS][36];
  __shared__ float bufA[1024][7], bufB[1024][7];
  scan_setup<false>(qs, gains, t, Da, Db, Dc, Dd, sW, sV, nullptr);
  int segstart = seg * R5SEGCH;
  int nch = min(R5SEGCH, NCH - segstart);
  int nact = nch >> 1;
  const float* F = ws + R5WS_F + ((long)row * NCH + segstart) * 6;
  float v[6] = {0,0,0,0,0,0};
  if (t < nact) {
    const float4* Fp = (const float4*)(F + 12 * t);
    float4 l0 = Fp[0], l1 = Fp[1], l2 = Fp[2];
    float f0[6] = {l0.x, l0.y, l0.z, l0.w, l1.x, l1.y};
    float f1[6] = {l1.z, l1.w, l2.x, l2.y, l2.z, l2.w};
    MV6(v, sW, f0, f1);
  }
  #pragma unroll
  for (int i = 0; i < 6; i++) bufA[t][i] = v[i];
  __syncthreads();
  float (*src)[7] = bufA, (*dst)[7] = bufB;
  for (int k = 0; k < R5ROUNDS; k++) {
    int d = 1 << k;
    float nv[6];
    if (t >= d) { MV6(nv, sV[k], src[t-d], src[t]); }
    else {
      #pragma unroll
      for (int i = 0; i < 6; i++) nv[i] = src[t][i];
    }
    #pragma unroll
    for (int i = 0; i < 6; i++) dst[t][i] = nv[i];
    __syncthreads();
    float (*tm)[7] = src; src = dst; dst = tm;
  }
  float* Ep = ws + R5WS_E + ((long)blockIdx.x * 1024 + t) * 6;
  if (t > 0) {
    #pragma unroll
    for (int i = 0; i < 6; i++) Ep[i] = src[t-1][i];
  } else {
    #pragma unroll
    for (int i = 0; i < 6; i++) Ep[i] = 0.0f;
  }
  if (t == nact - 1) {
    float* Tp = ws + R5WS_T + (long)blockIdx.x * 6;
    #pragma unroll
    for (int i = 0; i < 6; i++) Tp[i] = src[t][i];
  }
}

__global__ __launch_bounds__(1024) void kB2_inject(const float* __restrict__ qs,
                                                   const float* __restrict__ gains,
                                                   float* __restrict__ ws) {
  int seg = blockIdx.x & 7, row = blockIdx.x >> 3, t = threadIdx.x;
  __shared__ double Da[36], Db[36], Dc[36], Dd[36];
  __shared__ float sW[36], sV[R5ROUNDS][36], sG[36];
  __shared__ float sT[8][6], sO[6];
  scan_setup<true>(qs, gains, t, Da, Db, Dc, Dd, sW, sV, sG);
  if (t < 48) sT[t/6][t%6] = ws[R5WS_T + ((long)(row*8) + t/6) * 6 + t%6];
  __syncthreads();
  if (t == 0) {
    float o[6] = {0,0,0,0,0,0};
    for (int s2 = 0; s2 < seg; s2++) {
      float no[6];
      MV6(no, sG, o, sT[s2]);
      #pragma unroll
      for (int i = 0; i < 6; i++) o[i] = no[i];
    }
    #pragma unroll
    for (int i = 0; i < 6; i++) sO[i] = o[i];
  }
  __syncthreads();
  int segstart = seg * R5SEGCH;
  int nch = min(R5SEGCH, NCH - segstart);
  int nact = nch >> 1;
  if (t < nact) {
    float e[6];
    #pragma unroll
    for (int i = 0; i < 6; i++) e[i] = sO[i];
    for (int k = 0; k < R5ROUNDS; k++) {
      if ((t >> k) & 1) {
        float z[6] = {0,0,0,0,0,0}, ne[6];
        MV6(ne, sV[k], e, z);
        #pragma unroll
        for (int i = 0; i < 6; i++) e[i] = ne[i];
      }
    }
    const float* Er = ws + R5WS_E + ((long)blockIdx.x * 1024 + t) * 6;
    #pragma unroll
    for (int i = 0; i < 6; i++) e[i] += Er[i];
    float4* Fp = (float4*)(ws + R5WS_F + ((long)row * NCH + segstart) * 6 + 12 * t);
    float4 l0 = Fp[0], l1 = Fp[1];
    float f0[6] = {l0.x, l0.y, l0.z, l0.w, l1.x, l1.y};
    float e1[6];
    MV6(e1, sW, e, f0);
    Fp[0] = make_float4(e[0], e[1], e[2], e[3]);
    Fp[1] = make_float4(e[4], e[5], e1[0], e1[1]);
    Fp[2] = make_float4(e1[2], e1[3], e1[4], e1[5]);
  }
}

__global__ __launch_bounds__(256) void kC_emit(const float* __restrict__ x,
                                               const float* __restrict__ qs,
                                               const float* __restrict__ gains,
                                               float* __restrict__ y,
                                               const float* __restrict__ ws) {
  __shared__ float lds[4 * 2048];
  __shared__ float scoef[16];
  int wib = threadIdx.x >> 6, lane = threadIdx.x & 63;
  int gw = blockIdx.x * 4 + wib;
  int row = gw / WPR, wci = gw % WPR;
  long rowbase = (long)row * T_LEN;
  int s0 = wci << 11;
  int span4 = (min(2048, T_LEN - s0)) >> 2;
  const float4* xp = (const float4*)(x + rowbase + s0);
  float* slab = lds + (wib << 11);
  #pragma unroll
  for (int i = 0; i < 8; i++) {
    int s = (i << 6) + lane;
    int g = (s & ~7) | ((s & 7) ^ ((s >> 3) & 7));
    if (g < span4) GL2LDS(xp + g, slab + (i << 8));
  }
  COMPUTE_COEFS_TO_LDS(scoef, qs, gains);
  int ci = (wci << 6) + lane;
  float e0=0,e1=0,e2=0,e3=0,e4=0,e5=0;
  if (ci < NCH) {
    const float2* E = (const float2*)(ws + R5WS_F + ((long)row * NCH + ci) * 6);
    float2 p0 = E[0], p1 = E[1], p2 = E[2];
    e0=p0.x; e1=p0.y; e2=p1.x; e3=p1.y; e4=p2.x; e5=p2.y;
  }
  __syncthreads();
  if (ci < NCH) {
    LOAD_COEFS(scoef);
    float s11=e0, s21=e1, s12=e2, s22=e3, s13=e4, s23=e5;
    int rem = min(32, T_LEN - (ci << 5));
    int n4 = rem >> 2;
    float* rowp = slab + (lane << 5);
    int xr = lane & 7;
    float y3;
    for (int j4 = 0; j4 < n4; j4++) {
      float* p = rowp + ((j4 ^ xr) << 2);
      float4 v = *(const float4*)p;
      float4 o;
      CASCADE_STEP(v.x); o.x = y3;
      CASCADE_STEP(v.y); o.y = y3;
      CASCADE_STEP(v.z); o.z = y3;
      CASCADE_STEP(v.w); o.w = y3;
      *(float4*)p = o;
    }
  }
  __syncthreads();
  float4* yp = (float4*)(y + rowbase + s0);
  #pragma unroll
  for (int i = 0; i < 8; i++) {
    int g = (i << 6) + lane;
    int s = (g & ~7) | ((g & 7) ^ ((g >> 3) & 7));
    if (g < span4) yp[g] = *(const float4*)(lds + (wib << 11) + (s << 2));
  }
}

extern "C" void kernel_launch(void* const* d_in, const int* in_sizes, int n_in,
                              void* d_out, int out_size, void* d_ws, size_t ws_size,
                              hipStream_t stream) {
  const float* audio = (const float*)d_in[0];
  const float* qs    = (const float*)d_in[1];
  const float* gains = (const float*)d_in[2];
  float* out = (float*)d_out;
  float* ws  = (float*)d_ws;

  int dev = 0;
  (void)hipGetDevice(&dev);
  int nb = 0;
  (void)hipOccupancyMaxActiveBlocksPerMultiprocessor(&nb, fused, 256, 0);
  int ncu = 0;
  (void)hipDeviceGetAttribute(&ncu, hipDeviceAttributeMultiprocessorCount, dev);

  hipError_t st = hipErrorUnknown;
  if ((long)nb * ncu >= FNB) {
    void* kargs[] = {(void*)&audio, (void*)&qs, (void*)&gains, (void*)&out, (void*)&ws};
    st = hipLaunchCooperativeKernel((const void*)fused, dim3(FNB), dim3(256),
                                    kargs, 0, stream);
  }
  if (st != hipSuccess) {
    (void)hipGetLastError();
    hipLaunchKernelGGL(kA_states, dim3(R5NBLK), dim3(256), 0, stream, audio, qs, gains, ws);
    hipLaunchKernelGGL(kB1_scan, dim3(B_ROWS * 8), dim3(1024), 0, stream, qs, gains, ws);
    hipLaunchKernelGGL(kB2_inject, dim3(B_ROWS * 8), dim3(1024), 0, stream, qs, gains, ws);
    hipLaunchKernelGGL(kC_emit, dim3(R5NBLK), dim3(256), 0, stream, audio, qs, gains, out, ws);
  }
}

// Round 7
// 68.081 us; speedup vs baseline: 1.0234x; 1.0234x over previous
//
#include <hip/hip_runtime.h>
#include <math.h>

#define SR      44100.0
#define T_LEN   441000
#define B_ROWS  32
#define NCH     13782            // chunks per row (32 samples each; last = 8)
#define GCH     (B_ROWS * NCH)
#define WPR     216              // waves per row = ceil(NCH/64)
#define NWAVE   (B_ROWS * WPR)   // 6912
#define NBLK    (NWAVE / 4)      // 1728 blocks of 4 waves
#define NSEG    8
#define SEGCH   1724             // chunks/segment (segs 0..6); seg 7 = 1714 (both even)
#define ROUNDS  10

// ws layout (floats)
#define WS_MAT  0                // 12*36: U_k = W^(2^k) k=0..10, then G = W^1724
#define WS_T    512              // 256*6 segment totals
#define WS_F    4096             // GCH*6: finals -> relative entries (in place)

typedef __attribute__((address_space(1))) const void gconst_t;
typedef __attribute__((address_space(3))) void lds_t;
#define GL2LDS(gp, lp) __builtin_amdgcn_global_load_lds((gconst_t*)(gp), (lds_t*)(lp), 16, 0, 0)

// ---------------- shared helpers ----------------

#define COMPUTE_COEFS_TO_LDS(scoef, qs, gains) do { \
    if (threadIdx.x < 3) { \
      int f = threadIdx.x; \
      double cfq = 100.0 * exp(log(30.0) * (double)f / 3.0); \
      double w0 = 2.0 * M_PI * cfq / SR; \
      double alpha = sin(w0) / (2.0 * (double)qs[f]); \
      double Ag = exp((double)gains[f] * (2.302585092994045684 / 40.0)); \
      double a0 = 1.0 + alpha / Ag; \
      scoef[f*5+0] = (float)((1.0 + alpha * Ag) / a0); \
      scoef[f*5+1] = (float)((-2.0 * cos(w0)) / a0); \
      scoef[f*5+2] = (float)((1.0 - alpha * Ag) / a0); \
      scoef[f*5+3] = (float)((-2.0 * cos(w0)) / a0); \
      scoef[f*5+4] = (float)((1.0 - alpha / Ag) / a0); \
    } \
  } while (0)

#define LOAD_COEFS(cf) \
  const float b00=cf[0],b10=cf[1],b20=cf[2],a10=cf[3],a20=cf[4]; \
  const float b01=cf[5],b11=cf[6],b21=cf[7],a11=cf[8],a21=cf[9]; \
  const float b02=cf[10],b12=cf[11],b22=cf[12],a12=cf[13],a22=cf[14];

#define CASCADE_STEP(xx) do { \
    float y1 = fmaf(b00, (xx), s11); \
    s11 = fmaf(-a10, y1, fmaf(b10, (xx), s21)); \
    s21 = fmaf(-a20, y1, b20 * (xx)); \
    float y2 = fmaf(b01, y1, s12); \
    s12 = fmaf(-a11, y2, fmaf(b11, y1, s22)); \
    s22 = fmaf(-a21, y2, b21 * y1); \
    y3 = fmaf(b02, y2, s13); \
    s13 = fmaf(-a12, y3, fmaf(b12, y2, s23)); \
    s23 = fmaf(-a22, y3, b22 * y2); \
  } while (0)

#define MV6(dst, M, v, add) do { \
    _Pragma("unroll") \
    for (int _i = 0; _i < 6; _i++) { \
      float _s = (add)[_i]; \
      _Pragma("unroll") \
      for (int _k = 0; _k < 6; _k++) _s = fmaf((M)[_i*6+_k], (v)[_k], _s); \
      (dst)[_i] = _s; \
    } \
  } while (0)

__device__ __forceinline__ void mm6d(const double* X, const double* Y, double* Z, int t) {
  if (t < 36) {
    int i = t / 6, j = t % 6;
    double s = 0.0;
    #pragma unroll
    for (int k = 0; k < 6; k++) s += X[i*6+k] * Y[k*6+j];
    Z[t] = s;
  }
}

// ---------------- kA: chunk final states (zero entry) ----------------
// Per-wave slab: 64 chunks x 32 floats, linear. LDS float4-slot s holds global
// float4 g(s) = (s&~7)|((s&7)^((s>>3)&7)) — involution, line-local, bank-balanced.

__global__ __launch_bounds__(256) void kA_states(const float* __restrict__ x,
                                                 const float* __restrict__ qs,
                                                 const float* __restrict__ gains,
                                                 float* __restrict__ ws) {
  __shared__ float lds[4 * 2048];   // 4 waves x 8KB
  __shared__ float scoef[16];
  int wib = threadIdx.x >> 6, lane = threadIdx.x & 63;
  int gw = blockIdx.x * 4 + wib;
  int row = gw / WPR, wci = gw % WPR;
  long rowbase = (long)row * T_LEN;
  int s0 = wci << 11;
  int span4 = (min(2048, T_LEN - s0)) >> 2;          // 512 or 170
  const float4* xp = (const float4*)(x + rowbase + s0);
  float* slab = lds + (wib << 11);
  if (span4 == 512) {
    #pragma unroll
    for (int i = 0; i < 8; i++) {
      int s = (i << 6) + lane;
      int g = (s & ~7) | ((s & 7) ^ ((s >> 3) & 7));
      GL2LDS(xp + g, slab + (i << 8));
    }
  } else {
    #pragma unroll
    for (int i = 0; i < 8; i++) {
      int s = (i << 6) + lane;
      int g = (s & ~7) | ((s & 7) ^ ((s >> 3) & 7));
      if (g < span4) GL2LDS(xp + g, slab + (i << 8));
    }
  }
  COMPUTE_COEFS_TO_LDS(scoef, qs, gains);
  __syncthreads();
  int ci = (wci << 6) + lane;
  if (ci < NCH) {
    LOAD_COEFS(scoef);
    int rem = min(32, T_LEN - (ci << 5));
    int n4 = rem >> 2;
    const float* rowp = slab + (lane << 5);
    int xr = lane & 7;
    float s11=0,s21=0,s12=0,s22=0,s13=0,s23=0, y3;
    if (n4 == 8) {
      #pragma unroll
      for (int j4 = 0; j4 < 8; j4++) {
        float4 v = *(const float4*)(rowp + ((j4 ^ xr) << 2));
        CASCADE_STEP(v.x); CASCADE_STEP(v.y); CASCADE_STEP(v.z); CASCADE_STEP(v.w);
      }
    } else {
      for (int j4 = 0; j4 < n4; j4++) {
        float4 v = *(const float4*)(rowp + ((j4 ^ xr) << 2));
        CASCADE_STEP(v.x); CASCADE_STEP(v.y); CASCADE_STEP(v.z); CASCADE_STEP(v.w);
      }
    }
    (void)y3;
    float2* F = (float2*)(ws + WS_F + ((long)row * NCH + ci) * 6);
    F[0] = make_float2(s11, s21); F[1] = make_float2(s12, s22); F[2] = make_float2(s13, s23);
  }
}

// ---------------- per-block double-precision matrix setup ----------------
// Computes sW = A^32, sV[k] = W^(2*2^k) (k=0..9), sG = W^SEGCH.

__device__ __forceinline__ void scan_setup(const float* qs, const float* gains, int t,
                                           double* Da, double* Db, double* Dc, double* Dd,
                                           float* sW, float (*sV)[36], float* sG) {
  __shared__ double dco[3][5];
  if (t < 3) {
    int f = t;
    double cfq = 100.0 * exp(log(30.0) * (double)f / 3.0);
    double w0 = 2.0 * M_PI * cfq / SR;
    double alpha = sin(w0) / (2.0 * (double)qs[f]);
    double Ag = exp((double)gains[f] * (2.302585092994045684 / 40.0));
    double a0 = 1.0 + alpha / Ag;
    dco[f][0] = (1.0 + alpha * Ag) / a0;
    dco[f][1] = (-2.0 * cos(w0)) / a0;
    dco[f][2] = (1.0 - alpha * Ag) / a0;
    dco[f][3] = (-2.0 * cos(w0)) / a0;
    dco[f][4] = (1.0 - alpha / Ag) / a0;
  }
  __syncthreads();
  if (t == 0) {
    double u[7] = {0,0,0,0,0,0,1};
    for (int f = 0; f < 3; f++) {
      double b0=dco[f][0], b1=dco[f][1], b2=dco[f][2], a1=dco[f][3], a2=dco[f][4];
      double yv[7], s1p[7], s2p[7];
      for (int i = 0; i < 7; i++) {
        yv[i]  = b0 * u[i] + ((i == 2*f)   ? 1.0 : 0.0);
        s1p[i] = b1 * u[i] + ((i == 2*f+1) ? 1.0 : 0.0) - a1 * yv[i];
        s2p[i] = b2 * u[i] - a2 * yv[i];
      }
      for (int i = 0; i < 6; i++) { Da[(2*f)*6+i] = s1p[i]; Da[(2*f+1)*6+i] = s2p[i]; }
      for (int i = 0; i < 7; i++) u[i] = yv[i];
    }
  }
  if (t < 36) Dc[t] = (t % 7 == 0) ? 1.0 : 0.0;   // identity for G accumulation
  __syncthreads();
  mm6d(Da, Da, Db, t); __syncthreads();   // A^2
  mm6d(Db, Db, Da, t); __syncthreads();   // A^4
  mm6d(Da, Da, Db, t); __syncthreads();   // A^8
  mm6d(Db, Db, Da, t); __syncthreads();   // A^16
  mm6d(Da, Da, Db, t); __syncthreads();   // A^32 = W (Db)
  if (t < 36) sW[t] = (float)Db[t];
  mm6d(Db, Db, Da, t); __syncthreads();   // W^2 (Da) = V0
  double* cur = Da; double* oth = Db;
  double* Gc = Dc; double* Gd = Dd;
  // SEGCH = 1724: bits 2^(k+1) set for k in {1,2,3,4,6,8,9}
  #pragma unroll
  for (int k = 0; k < ROUNDS; k++) {
    if (t < 36) sV[k][t] = (float)cur[t];
    if ((SEGCH >> (k + 1)) & 1) {
      __syncthreads();
      mm6d(Gc, cur, Gd, t); __syncthreads();
      double* tm = Gc; Gc = Gd; Gd = tm;
    }
    if (k < ROUNDS - 1) {
      __syncthreads();
      mm6d(cur, cur, oth, t); __syncthreads();
      double* tm = cur; cur = oth; oth = tm;
    }
  }
  if (t < 36) sG[t] = (float)Gc[t];
  __syncthreads();
}

// ---------------- kB: segment scan -> relative entries in place + totals ----------------

__global__ __launch_bounds__(1024) void kB_scan(const float* __restrict__ qs,
                                                const float* __restrict__ gains,
                                                float* __restrict__ ws) {
  int seg = blockIdx.x & 7, row = blockIdx.x >> 3, t = threadIdx.x;
  __shared__ double Da[36], Db[36], Dc[36], Dd[36];
  __shared__ float sW[36], sV[ROUNDS][36], sG[36];
  __shared__ float bufA[1024][7], bufB[1024][7];
  scan_setup(qs, gains, t, Da, Db, Dc, Dd, sW, sV, sG);
  // block 0 publishes the float matrices for kC: U_k = W^(2^k) k=0..10, G
  if (blockIdx.x == 0 && t < 36) {
    ws[WS_MAT + t] = sW[t];
    #pragma unroll
    for (int k = 0; k < ROUNDS; k++) ws[WS_MAT + (k + 1) * 36 + t] = sV[k][t];
    ws[WS_MAT + 11 * 36 + t] = sG[t];
  }
  int segstart = seg * SEGCH;
  int nch = min(SEGCH, NCH - segstart);
  int nact = nch >> 1;             // 862 (857 for seg 7)
  float* F = ws + WS_F + ((long)row * NCH + segstart) * 6;
  float v[6] = {0,0,0,0,0,0};
  float f0[6] = {0,0,0,0,0,0};
  if (t < nact) {
    const float4* Fp = (const float4*)(F + 12 * t);   // 48t bytes: 16B-aligned
    float4 l0 = Fp[0], l1 = Fp[1], l2 = Fp[2];
    f0[0]=l0.x; f0[1]=l0.y; f0[2]=l0.z; f0[3]=l0.w; f0[4]=l1.x; f0[5]=l1.y;
    float f1[6] = {l1.z, l1.w, l2.x, l2.y, l2.z, l2.w};
    MV6(v, sW, f0, f1);            // pair total: chunk 2t final through chunk 2t+1
  }
  #pragma unroll
  for (int i = 0; i < 6; i++) bufA[t][i] = v[i];
  __syncthreads();
  float (*src)[7] = bufA, (*dst)[7] = bufB;
  for (int k = 0; k < ROUNDS; k++) {
    int d = 1 << k;
    float nv[6];
    if (t >= d) { MV6(nv, sV[k], src[t-d], src[t]); }
    else {
      #pragma unroll
      for (int i = 0; i < 6; i++) nv[i] = src[t][i];
    }
    #pragma unroll
    for (int i = 0; i < 6; i++) dst[t][i] = nv[i];
    __syncthreads();
    float (*tm)[7] = src; src = dst; dst = tm;
  }
  // segment total
  if (t == nact - 1) {
    float* Tp = ws + WS_T + (long)blockIdx.x * 6;
    #pragma unroll
    for (int i = 0; i < 6; i++) Tp[i] = src[t][i];
  }
  // relative entries written in place: entry(2t) = exclusive; entry(2t+1) = W*e + f0
  if (t < nact) {
    float e[6];
    if (t > 0) {
      #pragma unroll
      for (int i = 0; i < 6; i++) e[i] = src[t-1][i];
    } else {
      #pragma unroll
      for (int i = 0; i < 6; i++) e[i] = 0.0f;
    }
    float e1[6];
    MV6(e1, sW, e, f0);
    float4* Fp = (float4*)(F + 12 * t);
    Fp[0] = make_float4(e[0], e[1], e[2], e[3]);
    Fp[1] = make_float4(e[4], e[5], e1[0], e1[1]);
    Fp[2] = make_float4(e1[2], e1[3], e1[4], e1[5]);
  }
}

// ---------------- kC: absolutize entries + exact emit ----------------

__global__ __launch_bounds__(256) void kC_emit(const float* __restrict__ x,
                                               const float* __restrict__ qs,
                                               const float* __restrict__ gains,
                                               float* __restrict__ y,
                                               const float* __restrict__ ws) {
  __shared__ float lds[4 * 2048];
  __shared__ float scoef[16];
  __shared__ float smat[432];      // U_0..U_10, G
  __shared__ float sTT[96];        // totals for up to 2 rows x 8 segs
  __shared__ float sO[96];         // offsets: [rsel*8+seg][6]
  int tid = threadIdx.x;
  int wib = tid >> 6, lane = tid & 63;
  int gw = blockIdx.x * 4 + wib;
  int row = gw / WPR, wci = gw % WPR;
  int rowA = (blockIdx.x * 4) / WPR;
  long rowbase = (long)row * T_LEN;
  int s0 = wci << 11;
  int span4 = (min(2048, T_LEN - s0)) >> 2;
  const float4* xp = (const float4*)(x + rowbase + s0);
  float* slab = lds + (wib << 11);
  if (span4 == 512) {
    #pragma unroll
    for (int i = 0; i < 8; i++) {
      int s = (i << 6) + lane;
      int g = (s & ~7) | ((s & 7) ^ ((s >> 3) & 7));
      GL2LDS(xp + g, slab + (i << 8));
    }
  } else {
    #pragma unroll
    for (int i = 0; i < 8; i++) {
      int s = (i << 6) + lane;
      int g = (s & ~7) | ((s & 7) ^ ((s >> 3) & 7));
      if (g < span4) GL2LDS(xp + g, slab + (i << 8));
    }
  }
  // overlap: matrices + totals + coefs + relative-entry loads under staging
  for (int i = tid; i < 432; i += 256) smat[i] = ws[WS_MAT + i];
  {
    int rowB = (blockIdx.x * 4 + 3) / WPR;
    if (tid < 96) {
      int r = (tid < 48) ? rowA : rowB;
      int j = tid - ((tid < 48) ? 0 : 48);
      sTT[tid] = ws[WS_T + (long)r * 48 + j];
    }
  }
  COMPUTE_COEFS_TO_LDS(scoef, qs, gains);
  int ci = (wci << 6) + lane;
  float e0=0,e1v=0,e2=0,e3=0,e4=0,e5=0;
  if (ci < NCH) {
    const float2* E = (const float2*)(ws + WS_F + ((long)row * NCH + ci) * 6);
    float2 p0 = E[0], p1 = E[1], p2 = E[2];
    e0=p0.x; e1v=p0.y; e2=p1.x; e3=p1.y; e4=p2.x; e5=p2.y;
  }
  __syncthreads();
  // per-(row,seg) absolute offsets O = fold of previous segment totals with G
  if (tid < 16) {
    int rsel = tid >> 3, sg = tid & 7;
    const float* Gm = smat + 11 * 36;
    float o[6] = {0,0,0,0,0,0};
    for (int s2 = 0; s2 < sg; s2++) {
      float no[6];
      MV6(no, Gm, o, &sTT[rsel * 48 + s2 * 6]);
      #pragma unroll
      for (int i = 0; i < 6; i++) o[i] = no[i];
    }
    #pragma unroll
    for (int i = 0; i < 6; i++) sO[tid * 6 + i] = o[i];
  }
  __syncthreads();
  if (ci < NCH) {
    LOAD_COEFS(scoef);
    // absolute entry = rel_entry + W^d * O(row, seg)
    int seg = ci / SEGCH;
    int d = ci - seg * SEGCH;
    int rsel = (row == rowA) ? 0 : 1;
    const float* op = sO + (rsel * 8 + seg) * 6;
    float m[6];
    #pragma unroll
    for (int i = 0; i < 6; i++) m[i] = op[i];
    float z6[6] = {0,0,0,0,0,0};
    #pragma unroll
    for (int k = 0; k < 11; k++) {
      if ((d >> k) & 1) {
        float nm[6];
        MV6(nm, smat + k * 36, m, z6);
        #pragma unroll
        for (int i = 0; i < 6; i++) m[i] = nm[i];
      }
    }
    float s11=e0+m[0], s21=e1v+m[1], s12=e2+m[2], s22=e3+m[3], s13=e4+m[4], s23=e5+m[5];
    int rem = min(32, T_LEN - (ci << 5));
    int n4 = rem >> 2;
    float* rowp = slab + (lane << 5);
    int xr = lane & 7;
    float y3;
    if (n4 == 8) {
      #pragma unroll
      for (int j4 = 0; j4 < 8; j4++) {
        float* p = rowp + ((j4 ^ xr) << 2);
        float4 v = *(const float4*)p;
        float4 o;
        CASCADE_STEP(v.x); o.x = y3;
        CASCADE_STEP(v.y); o.y = y3;
        CASCADE_STEP(v.z); o.z = y3;
        CASCADE_STEP(v.w); o.w = y3;
        *(float4*)p = o;
      }
    } else {
      for (int j4 = 0; j4 < n4; j4++) {
        float* p = rowp + ((j4 ^ xr) << 2);
        float4 v = *(const float4*)p;
        float4 o;
        CASCADE_STEP(v.x); o.x = y3;
        CASCADE_STEP(v.y); o.y = y3;
        CASCADE_STEP(v.z); o.z = y3;
        CASCADE_STEP(v.w); o.w = y3;
        *(float4*)p = o;
      }
    }
  }
  __syncthreads();
  float4* yp = (float4*)(y + rowbase + s0);
  if (span4 == 512) {
    #pragma unroll
    for (int i = 0; i < 8; i++) {
      int g = (i << 6) + lane;
      int s = (g & ~7) | ((g & 7) ^ ((g >> 3) & 7));
      yp[g] = *(const float4*)(slab + (s << 2));
    }
  } else {
    #pragma unroll
    for (int i = 0; i < 8; i++) {
      int g = (i << 6) + lane;
      int s = (g & ~7) | ((g & 7) ^ ((g >> 3) & 7));
      if (g < span4) yp[g] = *(const float4*)(slab + (s << 2));
    }
  }
}

extern "C" void kernel_launch(void* const* d_in, const int* in_sizes, int n_in,
                              void* d_out, int out_size, void* d_ws, size_t ws_size,
                              hipStream_t stream) {
  const float* audio = (const float*)d_in[0];
  const float* qs    = (const float*)d_in[1];
  const float* gains = (const float*)d_in[2];
  float* out = (float*)d_out;
  float* ws  = (float*)d_ws;

  hipLaunchKernelGGL(kA_states, dim3(NBLK), dim3(256), 0, stream, audio, qs, gains, ws);
  hipLaunchKernelGGL(kB_scan, dim3(B_ROWS * NSEG), dim3(1024), 0, stream, qs, gains, ws);
  hipLaunchKernelGGL(kC_emit, dim3(NBLK), dim3(256), 0, stream, audio, qs, gains, out, ws);
}

// Round 8
// 62.615 us; speedup vs baseline: 1.1127x; 1.0873x over previous
//
#include <hip/hip_runtime.h>
#include <math.h>

#define SR      44100.0
#define T_LEN   441000
#define B_ROWS  32
#define NCH     13782            // chunks per row (32 samples each; last = 8)
#define GCH     (B_ROWS * NCH)
#define BPR     54               // blocks per row (256 chunks per block)
#define NBLK    (B_ROWS * BPR)   // 1728
#define NMAT    14               // W^(2^k), k=0..13  (W = A^32)

// ws layout (floats)
#define WS_MAT  0                // 14*36 = 504
#define WS_AG   512              // NBLK*6 block aggregates
#define WS_O    10880            // NBLK*6 block entry offsets
#define WS_F    21248            // GCH*6: relative entries (written by kA)

typedef __attribute__((address_space(1))) const void gconst_t;
typedef __attribute__((address_space(3))) void lds_t;
#define GL2LDS(gp, lp) __builtin_amdgcn_global_load_lds((gconst_t*)(gp), (lds_t*)(lp), 16, 0, 0)

// ---------------- shared helpers ----------------

// threads 0..2 compute per-filter coefs in double; write float coefs (+ LDS doubles)
#define COMPUTE_COEFS(scoef, dco, qs, gains) do { \
    if (threadIdx.x < 3) { \
      int f = threadIdx.x; \
      double cfq = 100.0 * exp(log(30.0) * (double)f / 3.0); \
      double w0 = 2.0 * M_PI * cfq / SR; \
      double alpha = sin(w0) / (2.0 * (double)qs[f]); \
      double Ag = exp((double)gains[f] * (2.302585092994045684 / 40.0)); \
      double a0 = 1.0 + alpha / Ag; \
      double c0 = (1.0 + alpha * Ag) / a0; \
      double c1 = (-2.0 * cos(w0)) / a0; \
      double c2 = (1.0 - alpha * Ag) / a0; \
      double c3 = c1; \
      double c4 = (1.0 - alpha / Ag) / a0; \
      if (dco) { double* dc = (double*)(dco); \
        dc[f*5+0]=c0; dc[f*5+1]=c1; dc[f*5+2]=c2; dc[f*5+3]=c3; dc[f*5+4]=c4; } \
      scoef[f*5+0]=(float)c0; scoef[f*5+1]=(float)c1; scoef[f*5+2]=(float)c2; \
      scoef[f*5+3]=(float)c3; scoef[f*5+4]=(float)c4; \
    } \
  } while (0)

#define LOAD_COEFS(cf) \
  const float b00=cf[0],b10=cf[1],b20=cf[2],a10=cf[3],a20=cf[4]; \
  const float b01=cf[5],b11=cf[6],b21=cf[7],a11=cf[8],a21=cf[9]; \
  const float b02=cf[10],b12=cf[11],b22=cf[12],a12=cf[13],a22=cf[14];

#define CASCADE_STEP(xx) do { \
    float y1 = fmaf(b00, (xx), s11); \
    s11 = fmaf(-a10, y1, fmaf(b10, (xx), s21)); \
    s21 = fmaf(-a20, y1, b20 * (xx)); \
    float y2 = fmaf(b01, y1, s12); \
    s12 = fmaf(-a11, y2, fmaf(b11, y1, s22)); \
    s22 = fmaf(-a21, y2, b21 * y1); \
    y3 = fmaf(b02, y2, s13); \
    s13 = fmaf(-a12, y3, fmaf(b12, y2, s23)); \
    s23 = fmaf(-a22, y3, b22 * y2); \
  } while (0)

#define MV6(dst, M, v, add) do { \
    _Pragma("unroll") \
    for (int _i = 0; _i < 6; _i++) { \
      float _s = (add)[_i]; \
      _Pragma("unroll") \
      for (int _k = 0; _k < 6; _k++) _s = fmaf((M)[_i*6+_k], (v)[_k], _s); \
      (dst)[_i] = _s; \
    } \
  } while (0)

__device__ __forceinline__ void mm6d(const double* X, const double* Y, double* Z, int t) {
  if (t < 36) {
    int i = t / 6, j = t % 6;
    double s = 0.0;
    #pragma unroll
    for (int k = 0; k < 6; k++) s += X[i*6+k] * Y[k*6+j];
    Z[t] = s;
  }
}

// Staging swizzle: LDS float4-slot s holds global float4 g(s) = (s&~7)|((s&7)^((s>>3)&7)).
// Involution, line-local (coalescing intact), ds_read_b128 bank-balanced.

// ---------------- kA: finals + in-block scan -> relative entries + aggregates ----------------

__global__ __launch_bounds__(256) void kA_scan(const float* __restrict__ x,
                                               const float* __restrict__ qs,
                                               const float* __restrict__ gains,
                                               float* __restrict__ ws) {
  __shared__ __align__(16) float lds[4 * 2048];   // audio slabs; later scan ping-pong bufs
  __shared__ double Da[36], Db[36];
  __shared__ double dco[15];
  __shared__ float sVm[NMAT][36];
  __shared__ float scoef[16];
  const int tid = threadIdx.x;
  const int wib = tid >> 6, lane = tid & 63;
  const int b = blockIdx.x;
  const int row = b / BPR, jb = b - row * BPR;
  const int wci = (jb << 2) + wib;
  long rowbase = (long)row * T_LEN;
  int s0 = wci << 11;
  int span4 = (min(2048, T_LEN - s0)) >> 2;        // 512, or 170 for last wave of row
  const float4* xp = (const float4*)(x + rowbase + s0);
  float* slab = lds + (wib << 11);
  if (span4 == 512) {
    #pragma unroll
    for (int i = 0; i < 8; i++) {
      int s = (i << 6) + lane;
      int g = (s & ~7) | ((s & 7) ^ ((s >> 3) & 7));
      GL2LDS(xp + g, slab + (i << 8));
    }
  } else {
    #pragma unroll
    for (int i = 0; i < 8; i++) {
      int s = (i << 6) + lane;
      int g = (s & ~7) | ((s & 7) ^ ((s >> 3) & 7));
      if (g < span4) GL2LDS(xp + g, slab + (i << 8));
    }
  }
  COMPUTE_COEFS(scoef, dco, qs, gains);
  // wave 0 only: matrix chain (DS ops are in-order within a wave; no block barriers)
  if (wib == 0) {
    if (lane == 0) {
      double u[7] = {0,0,0,0,0,0,1};   // current filter input as linear form over (S, x)
      for (int f = 0; f < 3; f++) {
        double c0=dco[f*5+0], c1=dco[f*5+1], c2=dco[f*5+2], c3=dco[f*5+3], c4=dco[f*5+4];
        double yv[7], s1p[7], s2p[7];
        for (int i = 0; i < 7; i++) {
          yv[i]  = c0 * u[i] + ((i == 2*f)   ? 1.0 : 0.0);
          s1p[i] = c1 * u[i] + ((i == 2*f+1) ? 1.0 : 0.0) - c3 * yv[i];
          s2p[i] = c2 * u[i] - c4 * yv[i];
        }
        for (int i = 0; i < 6; i++) { Da[(2*f)*6+i] = s1p[i]; Da[(2*f+1)*6+i] = s2p[i]; }
        for (int i = 0; i < 7; i++) u[i] = yv[i];
      }
    }
    double* cur = Da; double* oth = Db;
    #pragma unroll
    for (int s = 0; s < 5; s++) {                  // A -> A^32 = W
      mm6d(cur, cur, oth, lane);
      double* tm = cur; cur = oth; oth = tm;
    }
    #pragma unroll
    for (int k = 0; k < NMAT; k++) {               // publish W^(2^k)
      if (lane < 36) {
        float wv = (float)cur[lane];
        sVm[k][lane] = wv;
        if (b == 0) ws[WS_MAT + k*36 + lane] = wv;
      }
      if (k < NMAT - 1) {
        mm6d(cur, cur, oth, lane);
        double* tm = cur; cur = oth; oth = tm;
      }
    }
  }
  __syncthreads();

  // cascade over own chunk (32 samples) from zero state
  int ci = (jb << 8) + tid;                        // chunk index within row
  bool valid = ci < NCH;
  float f[6] = {0,0,0,0,0,0};
  if (valid) {
    LOAD_COEFS(scoef);
    int rem = min(32, T_LEN - (ci << 5));
    int n4 = rem >> 2;                             // 8, or 2 for the row's last chunk
    const float* rowp = slab + (lane << 5);
    int xr = lane & 7;
    float s11=0,s21=0,s12=0,s22=0,s13=0,s23=0, y3;
    if (n4 == 8) {
      #pragma unroll
      for (int j4 = 0; j4 < 8; j4++) {
        float4 v = *(const float4*)(rowp + ((j4 ^ xr) << 2));
        CASCADE_STEP(v.x); CASCADE_STEP(v.y); CASCADE_STEP(v.z); CASCADE_STEP(v.w);
      }
    } else {
      for (int j4 = 0; j4 < n4; j4++) {
        float4 v = *(const float4*)(rowp + ((j4 ^ xr) << 2));
        CASCADE_STEP(v.x); CASCADE_STEP(v.y); CASCADE_STEP(v.z); CASCADE_STEP(v.w);
      }
    }
    (void)y3;
    f[0]=s11; f[1]=s21; f[2]=s12; f[3]=s22; f[4]=s13; f[5]=s23;
  }
  __syncthreads();                                 // slab reads complete; reuse as scan bufs

  // in-block Hillis-Steele over 256 chunks (items: x -> W x + f)
  float* src = lds;          // 256*7 floats
  float* dst = lds + 1792;   // 256*7 floats
  #pragma unroll
  for (int i = 0; i < 6; i++) src[tid*7 + i] = f[i];
  __syncthreads();
  for (int k = 0; k < 8; k++) {
    int d = 1 << k;
    float nv[6];
    if (tid >= d) { MV6(nv, sVm[k], src + (tid-d)*7, src + tid*7); }
    else {
      #pragma unroll
      for (int i = 0; i < 6; i++) nv[i] = src[tid*7 + i];
    }
    #pragma unroll
    for (int i = 0; i < 6; i++) dst[tid*7 + i] = nv[i];
    __syncthreads();
    float* tm = src; src = dst; dst = tm;
  }
  // relative entry = exclusive prefix; write once (no finals to memory)
  if (valid) {
    float e[6];
    if (tid > 0) {
      #pragma unroll
      for (int i = 0; i < 6; i++) e[i] = src[(tid-1)*7 + i];
    } else {
      #pragma unroll
      for (int i = 0; i < 6; i++) e[i] = 0.0f;
    }
    float2* E = (float2*)(ws + WS_F + ((long)row * NCH + ci) * 6);
    E[0] = make_float2(e[0], e[1]); E[1] = make_float2(e[2], e[3]); E[2] = make_float2(e[4], e[5]);
  }
  // block aggregate (inclusive of all 256 chunks) — only needed for jb < 53
  if (tid == 255 && jb < BPR - 1) {
    #pragma unroll
    for (int i = 0; i < 6; i++) ws[WS_AG + ((long)row * BPR + jb) * 6 + i] = src[255*7 + i];
  }
}

// ---------------- kB: per-row scan of 54 block aggregates -> block offsets ----------------

__global__ __launch_bounds__(64) void kB_off(float* __restrict__ ws) {
  int row = blockIdx.x, j = threadIdx.x;
  __shared__ float sB[6][36];       // B^(2^k), B = W^256  (= sVm[8+k])
  __shared__ float buf[2][64][7];
  for (int i = j; i < 216; i += 64) sB[i/36][i%36] = ws[WS_MAT + (8 + i/36)*36 + (i%36)];
  float v[6] = {0,0,0,0,0,0};
  if (j < BPR - 1) {
    #pragma unroll
    for (int i = 0; i < 6; i++) v[i] = ws[WS_AG + ((long)row * BPR + j) * 6 + i];
  }
  __syncthreads();
  #pragma unroll
  for (int i = 0; i < 6; i++) buf[0][j][i] = v[i];
  __syncthreads();
  int cur = 0;
  for (int k = 0; k < 6; k++) {
    int d = 1 << k;
    float nv[6];
    if (j >= d) { MV6(nv, sB[k], buf[cur][j-d], buf[cur][j]); }
    else {
      #pragma unroll
      for (int i = 0; i < 6; i++) nv[i] = buf[cur][j][i];
    }
    #pragma unroll
    for (int i = 0; i < 6; i++) buf[cur^1][j][i] = nv[i];
    __syncthreads();
    cur ^= 1;
  }
  if (j < BPR) {
    float o[6];
    if (j > 0) {
      #pragma unroll
      for (int i = 0; i < 6; i++) o[i] = buf[cur][j-1][i];
    } else {
      #pragma unroll
      for (int i = 0; i < 6; i++) o[i] = 0.0f;
    }
    #pragma unroll
    for (int i = 0; i < 6; i++) ws[WS_O + ((long)row * BPR + j) * 6 + i] = o[i];
  }
}

// ---------------- kC: absolutize + exact emit ----------------

__global__ __launch_bounds__(256) void kC_emit(const float* __restrict__ x,
                                               const float* __restrict__ qs,
                                               const float* __restrict__ gains,
                                               float* __restrict__ y,
                                               const float* __restrict__ ws) {
  __shared__ __align__(16) float lds[4 * 2048];
  __shared__ float scoef[16];
  __shared__ float smat[288];       // W^(2^k), k=0..7
  const int tid = threadIdx.x;
  const int wib = tid >> 6, lane = tid & 63;
  const int b = blockIdx.x;
  const int row = b / BPR, jb = b - row * BPR;
  const int wci = (jb << 2) + wib;
  long rowbase = (long)row * T_LEN;
  int s0 = wci << 11;
  int span4 = (min(2048, T_LEN - s0)) >> 2;
  const float4* xp = (const float4*)(x + rowbase + s0);
  float* slab = lds + (wib << 11);
  if (span4 == 512) {
    #pragma unroll
    for (int i = 0; i < 8; i++) {
      int s = (i << 6) + lane;
      int g = (s & ~7) | ((s & 7) ^ ((s >> 3) & 7));
      GL2LDS(xp + g, slab + (i << 8));
    }
  } else {
    #pragma unroll
    for (int i = 0; i < 8; i++) {
      int s = (i << 6) + lane;
      int g = (s & ~7) | ((s & 7) ^ ((s >> 3) & 7));
      if (g < span4) GL2LDS(xp + g, slab + (i << 8));
    }
  }
  // overlap under staging: matrices, coefs, block offset, relative entries
  for (int i = tid; i < 288; i += 256) smat[i] = ws[WS_MAT + i];
  COMPUTE_COEFS(scoef, (double*)nullptr, qs, gains);
  float o6[6];
  {
    const float* Op = ws + WS_O + ((long)row * BPR + jb) * 6;
    #pragma unroll
    for (int i = 0; i < 6; i++) o6[i] = Op[i];
  }
  int ci = (jb << 8) + tid;
  bool valid = ci < NCH;
  float e0=0,e1v=0,e2=0,e3=0,e4=0,e5=0;
  if (valid) {
    const float2* E = (const float2*)(ws + WS_F + ((long)row * NCH + ci) * 6);
    float2 p0 = E[0], p1 = E[1], p2 = E[2];
    e0=p0.x; e1v=p0.y; e2=p1.x; e3=p1.y; e4=p2.x; e5=p2.y;
  }
  __syncthreads();
  if (valid) {
    LOAD_COEFS(scoef);
    // absolute entry = rel_entry + W^tid * O_block
    float m[6];
    #pragma unroll
    for (int i = 0; i < 6; i++) m[i] = o6[i];
    float z6[6] = {0,0,0,0,0,0};
    #pragma unroll
    for (int k = 0; k < 8; k++) {
      if ((tid >> k) & 1) {
        float nm[6];
        MV6(nm, smat + k*36, m, z6);
        #pragma unroll
        for (int i = 0; i < 6; i++) m[i] = nm[i];
      }
    }
    float s11=e0+m[0], s21=e1v+m[1], s12=e2+m[2], s22=e3+m[3], s13=e4+m[4], s23=e5+m[5];
    int rem = min(32, T_LEN - (ci << 5));
    int n4 = rem >> 2;
    float* rowp = slab + (lane << 5);
    int xr = lane & 7;
    float y3;
    if (n4 == 8) {
      #pragma unroll
      for (int j4 = 0; j4 < 8; j4++) {
        float* p = rowp + ((j4 ^ xr) << 2);
        float4 v = *(const float4*)p;
        float4 o;
        CASCADE_STEP(v.x); o.x = y3;
        CASCADE_STEP(v.y); o.y = y3;
        CASCADE_STEP(v.z); o.z = y3;
        CASCADE_STEP(v.w); o.w = y3;
        *(float4*)p = o;
      }
    } else {
      for (int j4 = 0; j4 < n4; j4++) {
        float* p = rowp + ((j4 ^ xr) << 2);
        float4 v = *(const float4*)p;
        float4 o;
        CASCADE_STEP(v.x); o.x = y3;
        CASCADE_STEP(v.y); o.y = y3;
        CASCADE_STEP(v.z); o.z = y3;
        CASCADE_STEP(v.w); o.w = y3;
        *(float4*)p = o;
      }
    }
  }
  __syncthreads();
  float4* yp = (float4*)(y + rowbase + s0);
  if (span4 == 512) {
    #pragma unroll
    for (int i = 0; i < 8; i++) {
      int g = (i << 6) + lane;
      int s = (g & ~7) | ((g & 7) ^ ((g >> 3) & 7));
      yp[g] = *(const float4*)(slab + (s << 2));
    }
  } else {
    #pragma unroll
    for (int i = 0; i < 8; i++) {
      int g = (i << 6) + lane;
      int s = (g & ~7) | ((g & 7) ^ ((g >> 3) & 7));
      if (g < span4) yp[g] = *(const float4*)(slab + (s << 2));
    }
  }
}

extern "C" void kernel_launch(void* const* d_in, const int* in_sizes, int n_in,
                              void* d_out, int out_size, void* d_ws, size_t ws_size,
                              hipStream_t stream) {
  const float* audio = (const float*)d_in[0];
  const float* qs    = (const float*)d_in[1];
  const float* gains = (const float*)d_in[2];
  float* out = (float*)d_out;
  float* ws  = (float*)d_ws;

  hipLaunchKernelGGL(kA_scan, dim3(NBLK), dim3(256), 0, stream, audio, qs, gains, ws);
  hipLaunchKernelGGL(kB_off, dim3(B_ROWS), dim3(64), 0, stream, ws);
  hipLaunchKernelGGL(kC_emit, dim3(NBLK), dim3(256), 0, stream, audio, qs, gains, out, ws);
}